// Round 1
// baseline (302.652 us; speedup 1.0000x reference)
//
#include <hip/hip_runtime.h>
#include <cstdint>

typedef unsigned int uint;
typedef unsigned short ushort;
typedef __bf16 bf16_t;
typedef bf16_t bf16x8 __attribute__((ext_vector_type(8)));
typedef float f32x4 __attribute__((ext_vector_type(4)));

#define LOG2E 1.44269504088896340736f

__device__ __forceinline__ ushort f2bf(float f) {
  uint x = __float_as_uint(f);
  x += 0x7fffu + ((x >> 16) & 1u);   // RNE to bf16
  return (ushort)(x >> 16);
}
__device__ __forceinline__ uint pack2(float lo, float hi) {
  return (uint)f2bf(lo) | ((uint)f2bf(hi) << 16);
}

// global -> LDS direct copy, 16B per lane; LDS dest is wave-uniform base + lane*16.
__device__ __forceinline__ void gload_lds16(const void* gsrc, void* ldsdst) {
  typedef const __attribute__((address_space(1))) unsigned int* gp_t;
  typedef __attribute__((address_space(3))) unsigned int* lp_t;
  __builtin_amdgcn_global_load_lds((gp_t)(uintptr_t)gsrc,
                                   (lp_t)(unsigned int)(uintptr_t)ldsdst,
                                   16, 0, 0);
}

// ---------------- fp32 -> bf16 convert (8 elems/thread) ----------------
__global__ __launch_bounds__(256) void cvt_kernel(const float* __restrict__ src,
                                                  ushort* __restrict__ dst, int n8) {
  int i = blockIdx.x * blockDim.x + threadIdx.x;
  if (i >= n8) return;
  const float4* s4 = (const float4*)src;
  float4 a = s4[i * 2], b = s4[i * 2 + 1];
  uint4 o;
  o.x = pack2(a.x, a.y); o.y = pack2(a.z, a.w);
  o.z = pack2(b.x, b.y); o.w = pack2(b.z, b.w);
  ((uint4*)dst)[i] = o;
}

// ---------------- GEMM: C[m][n] = sum_k A[m][k]*B[n][k] + bias[n] ----------------
// A: MxK bf16 row-major, B: NxK bf16 row-major. 128x128 tile, BK=32, 512 threads.
// LDS stores global chunk (cs ^ (row&3)) at [row][cs] (both-sides swizzle, linear LDS).
template <int OUT_BF16>
__global__ __launch_bounds__(512) void gemm_bt(const ushort* __restrict__ A,
                                               const ushort* __restrict__ B,
                                               const float* __restrict__ bias,
                                               void* __restrict__ Cout,
                                               int M, int N, int K) {
  __shared__ __align__(16) unsigned char As[8192];
  __shared__ __align__(16) unsigned char Bs[8192];
  const int tid = threadIdx.x;
  const int l = tid & 63, w = tid >> 6;      // 8 waves
  const int g = l >> 4, c = l & 15;
  const int wr = w >> 1, wc = w & 1;         // 4x2 wave grid, wave tile 32x64
  const int tm = blockIdx.y * 128, tn = blockIdx.x * 128;

  const int srow = w * 16 + (l >> 2);        // staging row 0..127
  const int schunk = (l & 3) ^ (srow & 3);   // pre-swizzled source chunk (16B units)
  const ushort* Ag = A + (size_t)(tm + srow) * K + schunk * 8;
  const ushort* Bg = B + (size_t)(tn + srow) * K + schunk * 8;
  void* AsBase = (void*)(As + w * 1024);
  void* BsBase = (void*)(Bs + w * 1024);

  f32x4 acc[2][4] = {};

  for (int kt = 0; kt < K; kt += 32) {
    __syncthreads();
    gload_lds16(Ag + kt, AsBase);
    gload_lds16(Bg + kt, BsBase);
    __syncthreads();
    bf16x8 af[2], bfr[4];
#pragma unroll
    for (int m = 0; m < 2; ++m) {
      int row = wr * 32 + m * 16 + c;
      af[m] = *(const bf16x8*)(As + row * 64 + ((g ^ (row & 3)) << 4));
    }
#pragma unroll
    for (int n = 0; n < 4; ++n) {
      int row = wc * 64 + n * 16 + c;
      bfr[n] = *(const bf16x8*)(Bs + row * 64 + ((g ^ (row & 3)) << 4));
    }
#pragma unroll
    for (int m = 0; m < 2; ++m)
#pragma unroll
      for (int n = 0; n < 4; ++n)
        acc[m][n] = __builtin_amdgcn_mfma_f32_16x16x32_bf16(af[m], bfr[n], acc[m][n], 0, 0, 0);
  }

#pragma unroll
  for (int n = 0; n < 4; ++n) {
    int col = tn + wc * 64 + n * 16 + c;
    float bv = bias[col];
#pragma unroll
    for (int m = 0; m < 2; ++m) {
      int row0 = tm + wr * 32 + m * 16 + g * 4;   // C/D: col=l&15, row=(l>>4)*4+i
#pragma unroll
      for (int i = 0; i < 4; ++i) {
        float vv = acc[m][n][i] + bv;
        if (OUT_BF16)
          ((ushort*)Cout)[(size_t)(row0 + i) * N + col] = f2bf(vv);
        else
          ((float*)Cout)[(size_t)(row0 + i) * N + col] = vv;
      }
    }
  }
}

// ---------------- fused rmsnorm (over dim) + 3-axis RoPE, fp32 -> bf16 ----------------
__global__ __launch_bounds__(256) void fuse_rms_rope(const float* __restrict__ pre,
                                                     const float* __restrict__ gw,
                                                     const float* __restrict__ fc,
                                                     const float* __restrict__ fs,
                                                     const int* __restrict__ pF,
                                                     const int* __restrict__ pH,
                                                     const int* __restrict__ pW,
                                                     ushort* __restrict__ outp, int dim) {
  const int p = blockIdx.x, t = threadIdx.x;
  const float* row = pre + (size_t)p * dim;
  float v[8];
  {
    float4 a = *(const float4*)(row + t * 8);
    float4 b = *(const float4*)(row + t * 8 + 4);
    v[0] = a.x; v[1] = a.y; v[2] = a.z; v[3] = a.w;
    v[4] = b.x; v[5] = b.y; v[6] = b.z; v[7] = b.w;
  }
  float ss = 0.f;
#pragma unroll
  for (int i = 0; i < 8; ++i) ss += v[i] * v[i];
#pragma unroll
  for (int off = 32; off; off >>= 1) ss += __shfl_xor(ss, off);
  __shared__ float wsum[4];
  if ((t & 63) == 0) wsum[t >> 6] = ss;
  __syncthreads();
  float rstd = rsqrtf((wsum[0] + wsum[1] + wsum[2] + wsum[3]) * (1.0f / dim) + 1e-6f);
  float gv[8];
  {
    float4 a = *(const float4*)(gw + t * 8);
    float4 b = *(const float4*)(gw + t * 8 + 4);
    gv[0] = a.x; gv[1] = a.y; gv[2] = a.z; gv[3] = a.w;
    gv[4] = b.x; gv[5] = b.y; gv[6] = b.z; gv[7] = b.w;
  }
#pragma unroll
  for (int i = 0; i < 8; ++i) v[i] = v[i] * rstd * gv[i];

  const int F = pF[0]; (void)F;
  const int H = pH[0], W = pW[0];
  const int hw = H * W;
  const int fr = p / hw;
  const int rem = p - fr * hw;
  const int hh = rem / W;
  const int ww = rem - hh * W;
  const int hd = dim / 16;        // head dim (128)
  const int cd = hd >> 1;         // 64 pairs/head; freqs row stride = cd
  const int c2 = cd / 3, c1 = cd - 2 * c2;
  const int j0 = ((t * 8) % hd) >> 1;   // first pair index within head

  uint ob[4];
#pragma unroll
  for (int q = 0; q < 4; ++q) {
    int j = j0 + q;
    int ri = (j < c1) ? fr : ((j < c1 + c2) ? hh : ww);
    float cs = fc[ri * cd + j];
    float sn = fs[ri * cd + j];
    float a = v[2 * q], b = v[2 * q + 1];
    ob[q] = pack2(a * cs - b * sn, a * sn + b * cs);
  }
  uint4 o4; o4.x = ob[0]; o4.y = ob[1]; o4.z = ob[2]; o4.w = ob[3];
  *(uint4*)(outp + (size_t)p * dim + t * 8) = o4;
}

// ---------------- V transpose: Vb[s][dim] -> Vt[dimcol][s] (bf16) ----------------
__global__ __launch_bounds__(256) void transpose_v(const ushort* __restrict__ Vb,
                                                   ushort* __restrict__ Vt,
                                                   int S_, int DIMc) {
  __shared__ ushort tile[64][66];
  const int s0 = blockIdx.x * 64, c0 = blockIdx.y * 64;
  const int t = threadIdx.x;
  const int r = t >> 2, cc = (t & 3) * 16;
  const ushort* src = Vb + (size_t)(s0 + r) * DIMc + c0 + cc;
  uint4 a = *(const uint4*)src;
  uint4 b = *(const uint4*)(src + 8);
  uint* dl = (uint*)&tile[r][cc];
  dl[0] = a.x; dl[1] = a.y; dl[2] = a.z; dl[3] = a.w;
  dl[4] = b.x; dl[5] = b.y; dl[6] = b.z; dl[7] = b.w;
  __syncthreads();
  uint o[8];
#pragma unroll
  for (int e = 0; e < 8; ++e)
    o[e] = (uint)tile[cc + 2 * e][r] | ((uint)tile[cc + 2 * e + 1][r] << 16);
  ushort* dst = Vt + (size_t)(c0 + r) * S_ + s0 + cc;
  uint4 q0; q0.x = o[0]; q0.y = o[1]; q0.z = o[2]; q0.w = o[3];
  uint4 q1; q1.x = o[4]; q1.y = o[5]; q1.z = o[6]; q1.w = o[7];
  *(uint4*)dst = q0;
  *(uint4*)(dst + 8) = q1;
}

// ---------------- flash attention, swapped QK^T, O^T = V^T P^T ----------------
// 256 threads / 4 waves; wave w owns q rows q0+w*16 .. +15 (lane's q-row = l&15).
__global__ __launch_bounds__(256) void attn_kernel(const ushort* __restrict__ Qb,
                                                   const ushort* __restrict__ Kb,
                                                   const ushort* __restrict__ Vt,
                                                   ushort* __restrict__ Ob,
                                                   const int* __restrict__ seq_lens,
                                                   int S_, int DIMc) {
  __shared__ __align__(16) unsigned char sk[16384];   // K tile [64][128] bf16 (swizzled)
  __shared__ __align__(16) unsigned char sv[16384];   // Vt tile [128][64] bf16 (swizzled)
  const int t = threadIdx.x, l = t & 63, w = t >> 6;
  const int g = l >> 4, c = l & 15;
  const int q0 = blockIdx.x * 64;
  const int head = blockIdx.y;
  const int kvlen = seq_lens[0];
  const int hd = DIMc / 16;                  // 128
  const float scale = rsqrtf((float)hd);

  // Q fragments (B operand): lane holds Q[q=l&15 of wave tile][k = ks*32 + g*8 + j]
  bf16x8 qf[4];
  {
    const ushort* qp = Qb + (size_t)(q0 + w * 16 + c) * DIMc + head * hd + g * 8;
#pragma unroll
    for (int ks = 0; ks < 4; ++ks) qf[ks] = *(const bf16x8*)(qp + ks * 32);
  }

  f32x4 ofr[8] = {};                          // O^T frags: row=d (g*4+i), col=q (c)
  float m_run = -1e30f, l_run = 0.f;

  const int krow0 = w * 16 + (l >> 4);        // K staging row base
  const int kcs = l & 15;
  const int vrow0 = w * 32 + (l >> 3);        // V staging row base
  const int vcs = l & 7;
  const int ntile = (kvlen + 63) >> 6;

  for (int tile = 0; tile < ntile; ++tile) {
    const int kv0 = tile * 64;
    __syncthreads();
#pragma unroll
    for (int it = 0; it < 4; ++it) {
      int kr = krow0 + it * 4;
      const ushort* ksrc = Kb + (size_t)(kv0 + kr) * DIMc + head * hd + ((kcs ^ (kr & 7)) * 8);
      gload_lds16(ksrc, (void*)(sk + w * 4096 + it * 1024));
      int vr = vrow0 + it * 8;
      const ushort* vsrc = Vt + (size_t)(head * hd + vr) * S_ + kv0 + ((vcs ^ (vr & 7)) * 8);
      gload_lds16(vsrc, (void*)(sv + w * 4096 + it * 1024));
    }
    __syncthreads();

    // S^T[key][q] = mfma(K rows as A, Q as B)
    f32x4 sfr[4] = {};
#pragma unroll
    for (int kf = 0; kf < 4; ++kf) {
      int row = kf * 16 + c;
#pragma unroll
      for (int ks = 0; ks < 4; ++ks) {
        bf16x8 kfrag = *(const bf16x8*)(sk + ((row * 256 + ks * 64 + g * 16) ^ ((row & 7) << 4)));
        sfr[kf] = __builtin_amdgcn_mfma_f32_16x16x32_bf16(kfrag, qf[ks], sfr[kf], 0, 0, 0);
      }
    }

    // per-lane online softmax over this lane's 16 keys, + reduce across 4 groups
    float tv[4][4];
    float mt = -1e30f;
#pragma unroll
    for (int kf = 0; kf < 4; ++kf)
#pragma unroll
      for (int i = 0; i < 4; ++i) {
        int key = kv0 + kf * 16 + g * 4 + i;
        float xx = sfr[kf][i] * scale;
        xx = (key < kvlen) ? xx : -1e30f;
        tv[kf][i] = xx;
        mt = fmaxf(mt, xx);
      }
    mt = fmaxf(mt, __shfl_xor(mt, 16));
    mt = fmaxf(mt, __shfl_xor(mt, 32));
    float m_new = fmaxf(m_run, mt);
    float fac = exp2f((m_run - m_new) * LOG2E);
    float ls = 0.f;
    uint pk[8];
#pragma unroll
    for (int kf = 0; kf < 4; ++kf) {
      float p0 = exp2f((tv[kf][0] - m_new) * LOG2E);
      float p1 = exp2f((tv[kf][1] - m_new) * LOG2E);
      float p2 = exp2f((tv[kf][2] - m_new) * LOG2E);
      float p3 = exp2f((tv[kf][3] - m_new) * LOG2E);
      ls += (p0 + p1) + (p2 + p3);
      pk[kf * 2] = pack2(p0, p1);        // keys kf*16+g*4 + {0,1}
      pk[kf * 2 + 1] = pack2(p2, p3);    // keys kf*16+g*4 + {2,3}
    }
    ls += __shfl_xor(ls, 16);
    ls += __shfl_xor(ls, 32);
    l_run = l_run * fac + ls;
    m_run = m_new;
#pragma unroll
    for (int df = 0; df < 8; ++df) ofr[df] *= fac;

    // redistribute P^T into B-fragments: lane needs keys 32s + 8g + {0..7} at q=c
    bf16x8 pfr[2];
#pragma unroll
    for (int s = 0; s < 2; ++s) {
      uint dw[4];
#pragma unroll
      for (int tt = 0; tt < 4; ++tt) {
        int src = ((((l & 16) >> 3) + (tt >> 1)) << 4) | c;   // ((g&1)*2 + tt/2)*16 + c
        uint lo = __shfl(pk[4 * s + (tt & 1)], src);
        uint hi = __shfl(pk[4 * s + 2 + (tt & 1)], src);
        dw[tt] = (l & 32) ? hi : lo;                          // g>=2 takes kf'=+1
      }
      union { uint4 u; bf16x8 b; } uu;
      uu.u.x = dw[0]; uu.u.y = dw[1]; uu.u.z = dw[2]; uu.u.w = dw[3];
      pfr[s] = uu.b;
    }

    // O^T += V^T (A) x P^T (B)
#pragma unroll
    for (int df = 0; df < 8; ++df) {
      int row = df * 16 + c;
#pragma unroll
      for (int kk = 0; kk < 2; ++kk) {
        bf16x8 vf = *(const bf16x8*)(sv + ((row * 128 + kk * 64 + g * 16) ^ ((row & 7) << 4)));
        ofr[df] = __builtin_amdgcn_mfma_f32_16x16x32_bf16(vf, pfr[kk], ofr[df], 0, 0, 0);
      }
    }
  }

  float inv = 1.0f / l_run;
  ushort* op = Ob + (size_t)(q0 + w * 16 + c) * DIMc + head * hd;
#pragma unroll
  for (int df = 0; df < 8; ++df)
#pragma unroll
    for (int i = 0; i < 4; ++i)
      op[df * 16 + g * 4 + i] = f2bf(ofr[df][i] * inv);
}

// ---------------- host ----------------
extern "C" void kernel_launch(void* const* d_in, const int* in_sizes, int n_in,
                              void* d_out, int out_size, void* d_ws, size_t ws_size,
                              hipStream_t stream) {
  const float* x  = (const float*)d_in[0];
  const float* fc = (const float*)d_in[1];
  const float* fs = (const float*)d_in[2];
  const float* Wq = (const float*)d_in[3];
  const float* bq = (const float*)d_in[4];
  const float* Wk = (const float*)d_in[5];
  const float* bk = (const float*)d_in[6];
  const float* Wv = (const float*)d_in[7];
  const float* bv = (const float*)d_in[8];
  const float* Wo = (const float*)d_in[9];
  const float* bo = (const float*)d_in[10];
  const float* gq = (const float*)d_in[11];
  const float* gk = (const float*)d_in[12];
  const int* seq  = (const int*)d_in[13];
  const int* pF   = (const int*)d_in[14];
  const int* pH   = (const int*)d_in[15];
  const int* pW   = (const int*)d_in[16];

  const int DIMc = in_sizes[4];          // 2048 (len of bq)
  const int S_   = in_sizes[0] / DIMc;   // 2048

  char* ws = (char*)d_ws;
  const size_t MB = 1024ull * 1024ull;
  ushort* xb   = (ushort*)(ws + 0 * MB);
  ushort* Wqb  = (ushort*)(ws + 8 * MB);
  ushort* Wkb  = (ushort*)(ws + 16 * MB);
  ushort* Wvb  = (ushort*)(ws + 24 * MB);
  ushort* Wob  = (ushort*)(ws + 32 * MB);
  float*  qpre = (float*)(ws + 40 * MB);
  float*  kpre = (float*)(ws + 56 * MB);
  ushort* Qb   = (ushort*)(ws + 72 * MB);
  ushort* Kb   = (ushort*)(ws + 80 * MB);
  ushort* Vb   = (ushort*)(ws + 88 * MB);
  ushort* Vt   = (ushort*)(ws + 96 * MB);
  ushort* Ob   = (ushort*)(ws + 40 * MB);  // aliases qpre (dead after fuse)

  const int nx8 = (S_ * DIMc) / 8;
  const int nw8 = (DIMc * DIMc) / 8;
  cvt_kernel<<<(nx8 + 255) / 256, 256, 0, stream>>>(x, xb, nx8);
  cvt_kernel<<<(nw8 + 255) / 256, 256, 0, stream>>>(Wq, Wqb, nw8);
  cvt_kernel<<<(nw8 + 255) / 256, 256, 0, stream>>>(Wk, Wkb, nw8);
  cvt_kernel<<<(nw8 + 255) / 256, 256, 0, stream>>>(Wv, Wvb, nw8);
  cvt_kernel<<<(nw8 + 255) / 256, 256, 0, stream>>>(Wo, Wob, nw8);

  dim3 gg(DIMc / 128, S_ / 128);
  gemm_bt<0><<<gg, 512, 0, stream>>>(xb, Wqb, bq, qpre, S_, DIMc, DIMc);
  gemm_bt<0><<<gg, 512, 0, stream>>>(xb, Wkb, bk, kpre, S_, DIMc, DIMc);
  gemm_bt<1><<<gg, 512, 0, stream>>>(xb, Wvb, bv, Vb, S_, DIMc, DIMc);

  fuse_rms_rope<<<S_, 256, 0, stream>>>(qpre, gq, fc, fs, pF, pH, pW, Qb, DIMc);
  fuse_rms_rope<<<S_, 256, 0, stream>>>(kpre, gk, fc, fs, pF, pH, pW, Kb, DIMc);

  transpose_v<<<dim3(S_ / 64, DIMc / 64), 256, 0, stream>>>(Vb, Vt, S_, DIMc);

  attn_kernel<<<dim3(S_ / 64, 16), 256, 0, stream>>>(Qb, Kb, Vt, Ob, seq, S_, DIMc);

  gemm_bt<0><<<gg, 512, 0, stream>>>(Ob, Wob, bo, (float*)d_out, S_, DIMc, DIMc);
}

// Round 2
// 197.763 us; speedup vs baseline: 1.5304x; 1.5304x over previous
//
#include <hip/hip_runtime.h>
#include <cstdint>
#include <cmath>

typedef unsigned int uint;
typedef unsigned short ushort;
typedef __bf16 bf16_t;
typedef bf16_t bf16x8 __attribute__((ext_vector_type(8)));
typedef float f32x4 __attribute__((ext_vector_type(4)));
typedef float f32x16 __attribute__((ext_vector_type(16)));

#define LOG2E 1.44269504088896340736f

__device__ __forceinline__ ushort f2bf(float f) {
  uint x = __float_as_uint(f);
  x += 0x7fffu + ((x >> 16) & 1u);   // RNE to bf16
  return (ushort)(x >> 16);
}
__device__ __forceinline__ uint pack2(float lo, float hi) {
  return (uint)f2bf(lo) | ((uint)f2bf(hi) << 16);
}
__device__ __forceinline__ uint cvt_pk_bf16(float lo, float hi) {
  uint r;
  asm("v_cvt_pk_bf16_f32 %0, %1, %2" : "=v"(r) : "v"(lo), "v"(hi));
  return r;
}

// global -> LDS direct copy, 16B per lane; LDS dest is wave-uniform base + lane*16.
__device__ __forceinline__ void gload_lds16(const void* gsrc, void* ldsdst) {
  typedef const __attribute__((address_space(1))) unsigned int* gp_t;
  typedef __attribute__((address_space(3))) unsigned int* lp_t;
  __builtin_amdgcn_global_load_lds((gp_t)(uintptr_t)gsrc,
                                   (lp_t)(unsigned int)(uintptr_t)ldsdst,
                                   16, 0, 0);
}

// ---------------- fp32 -> bf16 convert (8 elems/thread) ----------------
__global__ __launch_bounds__(256) void cvt_kernel(const float* __restrict__ src,
                                                  ushort* __restrict__ dst, int n8) {
  int i = blockIdx.x * blockDim.x + threadIdx.x;
  if (i >= n8) return;
  const float4* s4 = (const float4*)src;
  float4 a = s4[i * 2], b = s4[i * 2 + 1];
  uint4 o;
  o.x = pack2(a.x, a.y); o.y = pack2(a.z, a.w);
  o.z = pack2(b.x, b.y); o.w = pack2(b.z, b.w);
  ((uint4*)dst)[i] = o;
}

// ---------------- generic GEMM: C[m][n] = sum_k A[m][k]*B[n][k] + bias[n] ----------------
template <int OUT_BF16>
__global__ __launch_bounds__(512) void gemm_bt(const ushort* __restrict__ A,
                                               const ushort* __restrict__ B,
                                               const float* __restrict__ bias,
                                               void* __restrict__ Cout,
                                               int M, int N, int K) {
  __shared__ __align__(16) unsigned char As[8192];
  __shared__ __align__(16) unsigned char Bs[8192];
  const int tid = threadIdx.x;
  const int l = tid & 63, w = tid >> 6;
  const int g = l >> 4, c = l & 15;
  const int wr = w >> 1, wc = w & 1;
  const int tm = blockIdx.y * 128, tn = blockIdx.x * 128;

  const int srow = w * 16 + (l >> 2);
  const int schunk = (l & 3) ^ (srow & 3);
  const ushort* Ag = A + (size_t)(tm + srow) * K + schunk * 8;
  const ushort* Bg = B + (size_t)(tn + srow) * K + schunk * 8;
  void* AsBase = (void*)(As + w * 1024);
  void* BsBase = (void*)(Bs + w * 1024);

  f32x4 acc[2][4] = {};

  for (int kt = 0; kt < K; kt += 32) {
    __syncthreads();
    gload_lds16(Ag + kt, AsBase);
    gload_lds16(Bg + kt, BsBase);
    __syncthreads();
    bf16x8 af[2], bfr[4];
#pragma unroll
    for (int m = 0; m < 2; ++m) {
      int row = wr * 32 + m * 16 + c;
      af[m] = *(const bf16x8*)(As + row * 64 + ((g ^ (row & 3)) << 4));
    }
#pragma unroll
    for (int n = 0; n < 4; ++n) {
      int row = wc * 64 + n * 16 + c;
      bfr[n] = *(const bf16x8*)(Bs + row * 64 + ((g ^ (row & 3)) << 4));
    }
#pragma unroll
    for (int m = 0; m < 2; ++m)
#pragma unroll
      for (int n = 0; n < 4; ++n)
        acc[m][n] = __builtin_amdgcn_mfma_f32_16x16x32_bf16(af[m], bfr[n], acc[m][n], 0, 0, 0);
  }

#pragma unroll
  for (int n = 0; n < 4; ++n) {
    int col = tn + wc * 64 + n * 16 + c;
    float bv = bias[col];
#pragma unroll
    for (int m = 0; m < 2; ++m) {
      int row0 = tm + wr * 32 + m * 16 + g * 4;
#pragma unroll
      for (int i = 0; i < 4; ++i) {
        float vv = acc[m][n][i] + bv;
        if (OUT_BF16)
          ((ushort*)Cout)[(size_t)(row0 + i) * N + col] = f2bf(vv);
        else
          ((float*)Cout)[(size_t)(row0 + i) * N + col] = vv;
      }
    }
  }
}

// ---------------- fused QKV GEMM: B rows 0..2047 = Wq, 2048..4095 = Wk, 4096..6143 = Wv
// q/k pre-activations -> fp32 buffers; V -> bf16 written TRANSPOSED (Vt[d][s]).
__global__ __launch_bounds__(512) void gemm_qkv(const ushort* __restrict__ A,
                                                const ushort* __restrict__ B,
                                                const float* __restrict__ bq,
                                                const float* __restrict__ bk,
                                                const float* __restrict__ bv,
                                                float* __restrict__ qpre,
                                                float* __restrict__ kpre,
                                                ushort* __restrict__ Vt,
                                                int M, int Nfull, int K, int S_) {
  __shared__ __align__(16) unsigned char As[8192];
  __shared__ __align__(16) unsigned char Bs[8192];
  const int tid = threadIdx.x;
  const int l = tid & 63, w = tid >> 6;
  const int g = l >> 4, c = l & 15;
  const int wr = w >> 1, wc = w & 1;
  const int tm = blockIdx.y * 128, tn = blockIdx.x * 128;

  const int srow = w * 16 + (l >> 2);
  const int schunk = (l & 3) ^ (srow & 3);
  const ushort* Ag = A + (size_t)(tm + srow) * K + schunk * 8;
  const ushort* Bg = B + (size_t)(tn + srow) * K + schunk * 8;
  void* AsBase = (void*)(As + w * 1024);
  void* BsBase = (void*)(Bs + w * 1024);

  f32x4 acc[2][4] = {};

  for (int kt = 0; kt < K; kt += 32) {
    __syncthreads();
    gload_lds16(Ag + kt, AsBase);
    gload_lds16(Bg + kt, BsBase);
    __syncthreads();
    bf16x8 af[2], bfr[4];
#pragma unroll
    for (int m = 0; m < 2; ++m) {
      int row = wr * 32 + m * 16 + c;
      af[m] = *(const bf16x8*)(As + row * 64 + ((g ^ (row & 3)) << 4));
    }
#pragma unroll
    for (int n = 0; n < 4; ++n) {
      int row = wc * 64 + n * 16 + c;
      bfr[n] = *(const bf16x8*)(Bs + row * 64 + ((g ^ (row & 3)) << 4));
    }
#pragma unroll
    for (int m = 0; m < 2; ++m)
#pragma unroll
      for (int n = 0; n < 4; ++n)
        acc[m][n] = __builtin_amdgcn_mfma_f32_16x16x32_bf16(af[m], bfr[n], acc[m][n], 0, 0, 0);
  }

  const int sel = tn >> 11;   // uniform per block (2048 % 128 == 0)
  const float* bias = (sel == 0) ? bq : (sel == 1) ? bk : bv;
#pragma unroll
  for (int n = 0; n < 4; ++n) {
    int col = tn + wc * 64 + n * 16 + c;
    float bvv = bias[col & 2047];
#pragma unroll
    for (int m = 0; m < 2; ++m) {
      int row0 = tm + wr * 32 + m * 16 + g * 4;
      if (sel < 2) {
        float* outp = (sel == 0) ? qpre : kpre;
#pragma unroll
        for (int i = 0; i < 4; ++i)
          outp[(size_t)(row0 + i) * 2048 + (col & 2047)] = acc[m][n][i] + bvv;
      } else {
        uint2 o;
        o.x = pack2(acc[m][n][0] + bvv, acc[m][n][1] + bvv);
        o.y = pack2(acc[m][n][2] + bvv, acc[m][n][3] + bvv);
        *(uint2*)(Vt + (size_t)(col - 4096) * S_ + row0) = o;
      }
    }
  }
}

// ---------------- fused rmsnorm (over dim) + 3-axis RoPE + scale-fold, fp32 -> bf16 ----
__global__ __launch_bounds__(256) void fuse_rms_rope(const float* __restrict__ pre,
                                                     const float* __restrict__ gw,
                                                     const float* __restrict__ fc,
                                                     const float* __restrict__ fs,
                                                     const int* __restrict__ pF,
                                                     const int* __restrict__ pH,
                                                     const int* __restrict__ pW,
                                                     ushort* __restrict__ outp, int dim,
                                                     float fold) {
  const int p = blockIdx.x, t = threadIdx.x;
  const float* row = pre + (size_t)p * dim;
  float v[8];
  {
    float4 a = *(const float4*)(row + t * 8);
    float4 b = *(const float4*)(row + t * 8 + 4);
    v[0] = a.x; v[1] = a.y; v[2] = a.z; v[3] = a.w;
    v[4] = b.x; v[5] = b.y; v[6] = b.z; v[7] = b.w;
  }
  float ss = 0.f;
#pragma unroll
  for (int i = 0; i < 8; ++i) ss += v[i] * v[i];
#pragma unroll
  for (int off = 32; off; off >>= 1) ss += __shfl_xor(ss, off);
  __shared__ float wsum[4];
  if ((t & 63) == 0) wsum[t >> 6] = ss;
  __syncthreads();
  float rstd = rsqrtf((wsum[0] + wsum[1] + wsum[2] + wsum[3]) * (1.0f / dim) + 1e-6f);
  float gv[8];
  {
    float4 a = *(const float4*)(gw + t * 8);
    float4 b = *(const float4*)(gw + t * 8 + 4);
    gv[0] = a.x; gv[1] = a.y; gv[2] = a.z; gv[3] = a.w;
    gv[4] = b.x; gv[5] = b.y; gv[6] = b.z; gv[7] = b.w;
  }
#pragma unroll
  for (int i = 0; i < 8; ++i) v[i] = v[i] * rstd * gv[i];

  const int H = pH[0], W = pW[0];
  const int hw = H * W;
  const int fr = p / hw;
  const int rem = p - fr * hw;
  const int hh = rem / W;
  const int ww = rem - hh * W;
  const int hd = dim / 16;
  const int cd = hd >> 1;
  const int c2 = cd / 3, c1 = cd - 2 * c2;
  const int j0 = ((t * 8) % hd) >> 1;

  uint ob[4];
#pragma unroll
  for (int q = 0; q < 4; ++q) {
    int j = j0 + q;
    int ri = (j < c1) ? fr : ((j < c1 + c2) ? hh : ww);
    float cs = fc[ri * cd + j];
    float sn = fs[ri * cd + j];
    float a = v[2 * q], b = v[2 * q + 1];
    ob[q] = pack2((a * cs - b * sn) * fold, (a * sn + b * cs) * fold);
  }
  uint4 o4; o4.x = ob[0]; o4.y = ob[1]; o4.z = ob[2]; o4.w = ob[3];
  *(uint4*)(outp + (size_t)p * dim + t * 8) = o4;
}

// ---------------- flash attention, 32x32 MFMA, 4 q-subtiles x 2 KV-splits ----------------
// Per wave: 32 q rows (lane q = l&31), KVBLK=64. Swapped QK^T: S^T = mfma(K, Q).
// C/D layout (32x32): col = l&31, row = (r&3) + 8*(r>>2) + 4*(l>>5)  => key = 8g+4h+i.
// Q pre-scaled by scale*log2e; softmax in log2 domain, defer-max THR=8 (P <= 256).
__global__ __launch_bounds__(512, 2) void attn32(const ushort* __restrict__ Qb,
                                                 const ushort* __restrict__ Kb,
                                                 const ushort* __restrict__ Vt,
                                                 ushort* __restrict__ Ob,
                                                 const int* __restrict__ seq_lens,
                                                 int S_, int DIMc) {
  __shared__ __align__(16) unsigned char smem[66560];
  float* mlbuf = (float*)(smem + 65536);
  const int t = threadIdx.x, l = t & 63, w = t >> 6;
  const int qsub = w & 3, ksp = w >> 2;
  const int h = l >> 5, ql = l & 31;
  const int q0 = blockIdx.x * 128;
  const int head = blockIdx.y;
  const int kvlen = seq_lens[0];

  unsigned char* sk_s = smem + ksp * 16384;            // K tile [64][256B], swizzled ^row&15
  unsigned char* sv_s = smem + 32768 + ksp * 16384;    // V^T tile [128][128B], swizzled ^row&7

  bf16x8 qf[8];
  {
    const ushort* qp = Qb + (size_t)(q0 + qsub * 32 + ql) * DIMc + head * 128 + h * 8;
#pragma unroll
    for (int s = 0; s < 8; ++s) qf[s] = *(const bf16x8*)(qp + s * 16);
  }

  f32x16 ofr[4] = {};
  float m_run = -1e30f, l_run = 0.f;

  const int nt = (kvlen + 63) >> 6;
  const int half = (nt + 1) >> 1;
  const int tbase = ksp ? half : 0;
  const int mycnt = ksp ? (nt - half) : half;

  for (int tt = 0; tt < half; ++tt) {
    __syncthreads();
    if (tt < mycnt) {
      const int kv0 = (tbase + tt) * 64;
#pragma unroll
      for (int it = 0; it < 4; ++it) {
        int kr = qsub * 16 + it * 4 + (l >> 4);
        int kc = (l & 15) ^ (kr & 15);
        gload_lds16(Kb + (size_t)(kv0 + kr) * DIMc + head * 128 + kc * 8,
                    sk_s + qsub * 4096 + it * 1024);
        int vr = qsub * 32 + it * 8 + (l >> 3);
        int vc = (l & 7) ^ (vr & 7);
        gload_lds16(Vt + (size_t)(head * 128 + vr) * S_ + kv0 + vc * 8,
                    sv_s + qsub * 4096 + it * 1024);
      }
    }
    __syncthreads();
    if (tt >= mycnt) continue;
    const int kv0 = (tbase + tt) * 64;

    // S^T = K * Q  (A = K rows, B = Q cols)
    f32x16 sfr[2] = {};
#pragma unroll
    for (int kb = 0; kb < 2; ++kb) {
      const unsigned char* kbp = sk_s + (kb * 32 + ql) * 256;
      const int rx = (kb * 32 + ql) & 15;
#pragma unroll
      for (int s = 0; s < 8; ++s) {
        bf16x8 kf = *(const bf16x8*)(kbp + (((s * 2 + h) ^ rx) << 4));
        sfr[kb] = __builtin_amdgcn_mfma_f32_32x32x16_bf16(kf, qf[s], sfr[kb], 0, 0, 0);
      }
    }

    if (kv0 + 64 > kvlen) {
#pragma unroll
      for (int kb = 0; kb < 2; ++kb)
#pragma unroll
        for (int r = 0; r < 16; ++r) {
          int key = kv0 + kb * 32 + (r & 3) + 8 * (r >> 2) + 4 * h;
          if (key >= kvlen) sfr[kb][r] = -1e30f;
        }
    }

    float mt = -1e30f;
#pragma unroll
    for (int kb = 0; kb < 2; ++kb)
#pragma unroll
      for (int r = 0; r < 16; ++r) mt = fmaxf(mt, sfr[kb][r]);
    mt = fmaxf(mt, __shfl_xor(mt, 32));

    if (!__all(mt <= m_run + 8.0f)) {          // defer-max (log2 domain, P <= 256)
      float m_new = fmaxf(m_run, mt);
      float fac = __builtin_amdgcn_exp2f(m_run - m_new);
      l_run *= fac;
#pragma unroll
      for (int df = 0; df < 4; ++df) ofr[df] *= fac;
      m_run = m_new;
    }

    float ls = 0.f;
    uint u[2][4][2];    // [kb][g][pairword]: keys kb*32 + 8g + 4h + {2w, 2w+1}
#pragma unroll
    for (int kb = 0; kb < 2; ++kb)
#pragma unroll
      for (int G = 0; G < 4; ++G) {
        float p0 = __builtin_amdgcn_exp2f(sfr[kb][G * 4 + 0] - m_run);
        float p1 = __builtin_amdgcn_exp2f(sfr[kb][G * 4 + 1] - m_run);
        float p2 = __builtin_amdgcn_exp2f(sfr[kb][G * 4 + 2] - m_run);
        float p3 = __builtin_amdgcn_exp2f(sfr[kb][G * 4 + 3] - m_run);
        ls += (p0 + p1) + (p2 + p3);
        u[kb][G][0] = cvt_pk_bf16(p0, p1);
        u[kb][G][1] = cvt_pk_bf16(p2, p3);
      }
    ls += __shfl_xor(ls, 32);
    l_run += ls;

    // P^T B-fragments + PV: O^T += V^T * P^T
#pragma unroll
    for (int ks = 0; ks < 4; ++ks) {
      const int kb = ks >> 1, G0 = (ks & 1) * 2;
      uint own0 = h ? u[kb][G0 + 1][0] : u[kb][G0][0];
      uint own1 = h ? u[kb][G0 + 1][1] : u[kb][G0][1];
      uint snd0 = h ? u[kb][G0][0] : u[kb][G0 + 1][0];
      uint snd1 = h ? u[kb][G0][1] : u[kb][G0 + 1][1];
      uint rcv0 = __shfl_xor(snd0, 32);
      uint rcv1 = __shfl_xor(snd1, 32);
      union { uint4 q; bf16x8 b; } uu;
      uu.q.x = h ? rcv0 : own0;
      uu.q.y = h ? rcv1 : own1;
      uu.q.z = h ? own0 : rcv0;
      uu.q.w = h ? own1 : rcv1;
#pragma unroll
      for (int df = 0; df < 4; ++df) {
        const int row = df * 32 + ql;
        bf16x8 vf = *(const bf16x8*)(sv_s + row * 128 + (((ks * 2 + h) ^ (row & 7)) << 4));
        ofr[df] = __builtin_amdgcn_mfma_f32_32x32x16_bf16(vf, uu.b, ofr[df], 0, 0, 0);
      }
    }
  }

  // ---- flash merge of the two KV splits ----
  __syncthreads();
  if (ksp == 1) {
    if (h == 0) { mlbuf[qsub * 64 + ql] = m_run; mlbuf[qsub * 64 + 32 + ql] = l_run; }
    float* ob = (float*)(smem + qsub * 16384);
#pragma unroll
    for (int df = 0; df < 4; ++df)
#pragma unroll
      for (int r = 0; r < 16; ++r) {
        int d = df * 32 + (r & 3) + 8 * (r >> 2) + 4 * h;
        ob[d * 32 + ql] = ofr[df][r];
      }
  }
  __syncthreads();
  if (ksp == 0) {
    float m2 = mlbuf[qsub * 64 + ql], l2 = mlbuf[qsub * 64 + 32 + ql];
    float mstar = fmaxf(m_run, m2);
    float f1 = __builtin_amdgcn_exp2f(m_run - mstar);
    float f2 = (l2 > 0.f) ? __builtin_amdgcn_exp2f(m2 - mstar) : 0.f;
    float lstar = l_run * f1 + l2 * f2;
    float inv = 1.0f / lstar;
    float a1 = f1 * inv, a2 = f2 * inv;
    const float* ob = (const float*)(smem + qsub * 16384);
    ushort* orow = Ob + (size_t)(q0 + qsub * 32 + ql) * DIMc + head * 128;
#pragma unroll
    for (int df = 0; df < 4; ++df)
#pragma unroll
      for (int G = 0; G < 4; ++G) {
        int d0 = df * 32 + 8 * G + 4 * h;
        float v0 = ofr[df][G * 4 + 0] * a1 + ob[(d0 + 0) * 32 + ql] * a2;
        float v1 = ofr[df][G * 4 + 1] * a1 + ob[(d0 + 1) * 32 + ql] * a2;
        float v2 = ofr[df][G * 4 + 2] * a1 + ob[(d0 + 2) * 32 + ql] * a2;
        float v3 = ofr[df][G * 4 + 3] * a1 + ob[(d0 + 3) * 32 + ql] * a2;
        uint2 o; o.x = pack2(v0, v1); o.y = pack2(v2, v3);
        *(uint2*)(orow + d0) = o;
      }
  }
}

// ---------------- host ----------------
extern "C" void kernel_launch(void* const* d_in, const int* in_sizes, int n_in,
                              void* d_out, int out_size, void* d_ws, size_t ws_size,
                              hipStream_t stream) {
  const float* x  = (const float*)d_in[0];
  const float* fc = (const float*)d_in[1];
  const float* fs = (const float*)d_in[2];
  const float* Wq = (const float*)d_in[3];
  const float* bq = (const float*)d_in[4];
  const float* Wk = (const float*)d_in[5];
  const float* bk = (const float*)d_in[6];
  const float* Wv = (const float*)d_in[7];
  const float* bv = (const float*)d_in[8];
  const float* Wo = (const float*)d_in[9];
  const float* bo = (const float*)d_in[10];
  const float* gq = (const float*)d_in[11];
  const float* gk = (const float*)d_in[12];
  const int* seq  = (const int*)d_in[13];
  const int* pF   = (const int*)d_in[14];
  const int* pH   = (const int*)d_in[15];
  const int* pW   = (const int*)d_in[16];

  const int DIMc = in_sizes[4];          // 2048
  const int S_   = in_sizes[0] / DIMc;   // 2048

  char* ws = (char*)d_ws;
  const size_t MB = 1024ull * 1024ull;
  ushort* xb    = (ushort*)(ws + 0 * MB);
  ushort* Wqkvb = (ushort*)(ws + 8 * MB);    // [6144][2048] bf16 = 24 MB
  ushort* Wob   = (ushort*)(ws + 32 * MB);
  float*  qpre  = (float*)(ws + 40 * MB);
  float*  kpre  = (float*)(ws + 56 * MB);
  ushort* Qb    = (ushort*)(ws + 72 * MB);
  ushort* Kb    = (ushort*)(ws + 80 * MB);
  ushort* Vt    = (ushort*)(ws + 88 * MB);   // [2048 feat][2048 tok] bf16
  ushort* Ob    = (ushort*)(ws + 40 * MB);   // aliases qpre (dead after fuse)

  const int nx8 = (S_ * DIMc) / 8;
  const int nw8 = (DIMc * DIMc) / 8;
  cvt_kernel<<<(nx8 + 255) / 256, 256, 0, stream>>>(x, xb, nx8);
  cvt_kernel<<<(nw8 + 255) / 256, 256, 0, stream>>>(Wq, Wqkvb, nw8);
  cvt_kernel<<<(nw8 + 255) / 256, 256, 0, stream>>>(Wk, Wqkvb + (size_t)DIMc * DIMc, nw8);
  cvt_kernel<<<(nw8 + 255) / 256, 256, 0, stream>>>(Wv, Wqkvb + 2 * (size_t)DIMc * DIMc, nw8);
  cvt_kernel<<<(nw8 + 255) / 256, 256, 0, stream>>>(Wo, Wob, nw8);

  // fused QKV GEMM: M=S_, N=3*DIMc
  gemm_qkv<<<dim3(3 * DIMc / 128, S_ / 128), 512, 0, stream>>>(
      xb, Wqkvb, bq, bk, bv, qpre, kpre, Vt, S_, 3 * DIMc, DIMc, S_);

  const float foldq = 1.44269504088896340736f / sqrtf((float)(DIMc / 16));
  fuse_rms_rope<<<S_, 256, 0, stream>>>(qpre, gq, fc, fs, pF, pH, pW, Qb, DIMc, foldq);
  fuse_rms_rope<<<S_, 256, 0, stream>>>(kpre, gk, fc, fs, pF, pH, pW, Kb, DIMc, 1.0f);

  attn32<<<dim3(S_ / 128, 16), 512, 0, stream>>>(Qb, Kb, Vt, Ob, seq, S_, DIMc);

  gemm_bt<0><<<dim3(DIMc / 128, S_ / 128), 512, 0, stream>>>(
      Ob, Wob, bo, (float*)d_out, S_, DIMc, DIMc);
}